// Round 4
// baseline (34.210 us; speedup 1.0000x reference)
//
#include <hip/hip_runtime.h>

// HalutMatmul forward on MI355X.
// Per row n: h[c][p] = sum_d I[n, c*9+d] * A[c][d][p]   (c=0..15, p=0..3)
//            code_c  = 4-level tree descent: bit_l = (h[c][l] > T[c*15 + node_l])
//            out[n][m] = sum_c L[m][c][code_c]
// S and B from the reference are structural and baked into the control flow.
//
// Round-4: occupancy attack. 2 threads/row (acc[32] each, codes swapped via
// shfl_xor), bf16 LUT in 32 KiB LDS gathered as ds_read_b128 with chunk-XOR
// swizzle, f64 hash/tree unchanged (exact codes). LDS ~39.3 KiB + VGPR<=128
// -> 4 blocks/CU, 16 waves/CU, whole grid resident.

#define NROWS (1024 * 128)

__global__ __launch_bounds__(256, 4) void halut_fwd(
    const float* __restrict__ I,
    const float* __restrict__ A,
    const float* __restrict__ T,
    const float* __restrict__ L,
    float* __restrict__ out)
{
    // 32 KiB: bf16 LUT as uint4 chunks. Chunk (q=m8, col=c*16+p) lives at
    // uint4 index q*256 + c*16 + (p ^ q); dword d holds m=8q+2d (lo), 8q+2d+1 (hi).
    // Reused as float[128][64] output staging after the gather.
    __shared__ uint32_t sTab[8192];
    __shared__ double   sA[576];   // A promoted to f64: [c][d][p]
    __shared__ double   sT[240];   // thresholds, f64

    const int tid = threadIdx.x;

    {   // ---- stage L: thread t owns column col = t ----
        const int hi4 = tid & 0xF0, p = tid & 15;
        #pragma unroll
        for (int q2 = 0; q2 < 32; ++q2) {            // m pair (2*q2, 2*q2+1)
            const uint32_t ua = __float_as_uint(L[(2 * q2)     * 256 + tid]);
            const uint32_t ub = __float_as_uint(L[(2 * q2 + 1) * 256 + tid]);
            const uint32_t ba = (ua + 0x7fffu + ((ua >> 16) & 1u)) >> 16; // RTNE
            const uint32_t bb = (ub + 0x7fffu + ((ub >> 16) & 1u)) >> 16;
            const int q = q2 >> 2, d = q2 & 3;
            sTab[((q << 8) + hi4 + (p ^ q)) * 4 + d] = (bb << 16) | ba;
        }
    }
    for (int i = tid; i < 576; i += 256) sA[i] = (double)A[i];
    if (tid < 240) sT[tid] = (double)T[tid];
    __syncthreads();

    const int lr  = tid >> 1;            // local row 0..127
    const int mh  = tid & 1;             // which half of m this thread owns
    const int row = blockIdx.x * 128 + lr;
    const float* rp = I + (size_t)row * 144 + mh * 72;  // my 8 codebooks' input

    // ---- hash + tree for my 8 codebooks; pack codes 4b each ----
    uint32_t mycodes = 0;
    #pragma unroll
    for (int g = 0; g < 2; ++g) {                    // 4 codebooks per group
        float4 buf[9];
        const float4* rv = (const float4*)(rp + g * 36);  // 16B-aligned
        #pragma unroll
        for (int i = 0; i < 9; ++i) buf[i] = rv[i];
        const float* bf = (const float*)buf;

        #pragma unroll
        for (int cc = 0; cc < 4; ++cc) {
            const int cl = g * 4 + cc;               // 0..7 local codebook
            const int c  = mh * 8 + cl;              // global codebook
            double h0 = 0.0, h1 = 0.0, h2 = 0.0, h3 = 0.0;
            #pragma unroll
            for (int d = 0; d < 9; ++d) {
                const double  x  = (double)bf[cc * 9 + d];
                const double* ap = &sA[(c * 9 + d) * 4];
                h0 = fma(x, ap[0], h0);
                h1 = fma(x, ap[1], h1);
                h2 = fma(x, ap[2], h2);
                h3 = fma(x, ap[3], h3);
            }
            const double* tp = &sT[c * 15];
            int p;
            p =         (h0 > tp[0]);
            p = 2 * p + (h1 > tp[1 + p]);
            p = 2 * p + (h2 > tp[3 + p]);
            p = 2 * p + (h3 > tp[7 + p]);
            mycodes |= (uint32_t)p << (4 * cl);
        }
    }
    const uint32_t other = __shfl_xor(mycodes, 1);   // partner's 8 codes
    const uint32_t lo = mh ? other : mycodes;        // codes c=0..7
    const uint32_t hi = mh ? mycodes : other;        // codes c=8..15

    // ---- gather-accumulate my 32 m-values over all 16 codebooks ----
    float acc[32];
    #pragma unroll
    for (int m = 0; m < 32; ++m) acc[m] = 0.0f;

    const uint4* tab = (const uint4*)sTab;
    #pragma unroll 4
    for (int c = 0; c < 16; ++c) {
        const int p = (int)(((c < 8 ? lo : hi) >> (4 * (c & 7))) & 15u);
        #pragma unroll
        for (int i = 0; i < 4; ++i) {
            const int q = mh * 4 + i;                // m-chunk: m in [8q, 8q+8)
            const uint4 w = tab[(q << 8) + (c << 4) + (p ^ q)];
            const int mb = i << 3;
            acc[mb + 0] += __uint_as_float(w.x << 16);
            acc[mb + 1] += __uint_as_float(w.x & 0xffff0000u);
            acc[mb + 2] += __uint_as_float(w.y << 16);
            acc[mb + 3] += __uint_as_float(w.y & 0xffff0000u);
            acc[mb + 4] += __uint_as_float(w.z << 16);
            acc[mb + 5] += __uint_as_float(w.z & 0xffff0000u);
            acc[mb + 6] += __uint_as_float(w.w << 16);
            acc[mb + 7] += __uint_as_float(w.w & 0xffff0000u);
        }
    }

    // ---- single-pass output transpose through sTab (LUT is dead now) ----
    __syncthreads();
    float* sO = (float*)sTab;            // [128 rows][64 m], 16B-chunk swizzle
    #pragma unroll
    for (int mc = 0; mc < 8; ++mc) {
        const int chunk = mh * 8 + mc;   // float4 chunk within the row
        *(float4*)&sO[(lr << 6) + ((chunk ^ (lr & 15)) << 2)] =
            make_float4(acc[4*mc], acc[4*mc+1], acc[4*mc+2], acc[4*mc+3]);
    }
    __syncthreads();

    float4* op = (float4*)(out + (size_t)blockIdx.x * (128 * 64));
    #pragma unroll
    for (int j = 0; j < 8; ++j) {        // 2048 float4 = 32 KiB, contiguous
        const int F  = tid + (j << 8);
        const int r2 = F >> 4;
        const int m2 = F & 15;
        op[F] = *(const float4*)&sO[(r2 << 6) + ((m2 ^ (r2 & 15)) << 2)];
    }
}

extern "C" void kernel_launch(void* const* d_in, const int* in_sizes, int n_in,
                              void* d_out, int out_size, void* d_ws, size_t ws_size,
                              hipStream_t stream) {
    const float* I = (const float*)d_in[0];
    const float* A = (const float*)d_in[1];
    const float* T = (const float*)d_in[2];
    const float* L = (const float*)d_in[3];
    float* outp = (float*)d_out;

    const int nblocks = NROWS / 128;   // 1024 blocks x 256 threads, 2 thr/row
    halut_fwd<<<nblocks, 256, 0, stream>>>(I, A, T, L, outp);
}

// Round 5
// 31.390 us; speedup vs baseline: 1.0898x; 1.0898x over previous
//
#include <hip/hip_runtime.h>
#include <hip/hip_fp16.h>

// HalutMatmul forward on MI355X.
// Per row n: h[c][p] = sum_d I[n, c*9+d] * A[c][d][p]   (c=0..15, p=0..3)
//            code_c  = 4-level tree descent: bit_l = (h[c][l] > T[c*15 + node_l])
//            out[n][m] = sum_c L[m][c][code_c]
// S and B from the reference are structural and baked into the control flow.
//
// Round-5: round-4 occupancy structure (2 threads/row, 16 waves/CU) with a
// conflict-free, unpack-free gather:
//  - LUT as f16 in [m-quad][col] layout; ds_read_b64 gather -> bank-pair = p,
//    only the 2 mh-halves alias per pair => 2-way (free, m136).
//  - v_pk_add_f16 accumulation (16 half2 regs), no bit-unpack at all.
//  - f64 hash/tree decisions unchanged (exact codes); f16 table err ~6e-5/entry.

#define NROWS (1024 * 128)

__global__ __launch_bounds__(256, 4) void halut_fwd(
    const float* __restrict__ I,
    const float* __restrict__ A,
    const float* __restrict__ T,
    const float* __restrict__ L,
    float* __restrict__ out)
{
    // 32 KiB: f16 LUT, uint2[q8][col]: q8 = m/4 (0..15), col = c*16+p (0..255);
    // dword x = halves (m=4q8, 4q8+1), dword y = (4q8+2, 4q8+3).
    // Reused as float[128][64] output staging after the gather.
    __shared__ uint32_t sBuf[8192];
    __shared__ double   sA[576];   // A promoted to f64: [c][d][p]
    __shared__ double   sT[240];   // thresholds, f64

    const int tid = threadIdx.x;

    {   // ---- stage L: thread t owns column col = t; coalesced loads ----
        uint2* lut2 = (uint2*)sBuf;
        #pragma unroll
        for (int q = 0; q < 16; ++q) {
            const float a = L[(4 * q + 0) * 256 + tid];
            const float b = L[(4 * q + 1) * 256 + tid];
            const float c = L[(4 * q + 2) * 256 + tid];
            const float d = L[(4 * q + 3) * 256 + tid];
            uint2 u;
            u.x = ((uint32_t)__half_as_ushort(__float2half_rn(b)) << 16)
                |  (uint32_t)__half_as_ushort(__float2half_rn(a));
            u.y = ((uint32_t)__half_as_ushort(__float2half_rn(d)) << 16)
                |  (uint32_t)__half_as_ushort(__float2half_rn(c));
            lut2[q * 256 + tid] = u;
        }
    }
    for (int i = tid; i < 576; i += 256) sA[i] = (double)A[i];
    if (tid < 240) sT[tid] = (double)T[tid];
    __syncthreads();

    const int lr  = tid >> 1;            // local row 0..127
    const int mh  = tid & 1;             // which half of m / which 8 codebooks
    const int row = blockIdx.x * 128 + lr;
    const float* rp = I + (size_t)row * 144 + mh * 72;

    // ---- load my 72 input floats in one burst (VMEM ILP) ----
    float4 buf[18];
    {
        const float4* rv = (const float4*)rp;   // 288B offset -> 16B aligned
        #pragma unroll
        for (int i = 0; i < 18; ++i) buf[i] = rv[i];
    }
    const float* bf = (const float*)buf;

    // ---- hash + tree for my 8 codebooks; pack codes 4b each ----
    uint32_t mycodes = 0;
    #pragma unroll
    for (int cl = 0; cl < 8; ++cl) {
        const int c = mh * 8 + cl;               // global codebook
        double h0 = 0.0, h1 = 0.0, h2 = 0.0, h3 = 0.0;
        #pragma unroll
        for (int d = 0; d < 9; ++d) {
            const double  x  = (double)bf[cl * 9 + d];
            const double* ap = &sA[(c * 9 + d) * 4];
            h0 = fma(x, ap[0], h0);
            h1 = fma(x, ap[1], h1);
            h2 = fma(x, ap[2], h2);
            h3 = fma(x, ap[3], h3);
        }
        const double* tp = &sT[c * 15];
        int p;
        p =         (h0 > tp[0]);
        p = 2 * p + (h1 > tp[1 + p]);
        p = 2 * p + (h2 > tp[3 + p]);
        p = 2 * p + (h3 > tp[7 + p]);
        mycodes |= (uint32_t)p << (4 * cl);
    }
    const uint32_t other = __shfl_xor(mycodes, 1);   // partner's 8 codes
    const uint32_t lo = mh ? other : mycodes;        // codes c=0..7
    const uint32_t hi = mh ? mycodes : other;        // codes c=8..15

    // ---- gather-accumulate my 32 m-values (packed-half adds) ----
    __half2 acc2[16];
    const __half2 zero = __floats2half2_rn(0.f, 0.f);
    #pragma unroll
    for (int k = 0; k < 16; ++k) acc2[k] = zero;

    const uint2* lut2 = (const uint2*)sBuf;
    #pragma unroll 4
    for (int c = 0; c < 16; ++c) {
        const int p   = (int)(((c < 8 ? lo : hi) >> (4 * (c & 7))) & 15u);
        const int col = (c << 4) + p;
        #pragma unroll
        for (int i = 0; i < 8; ++i) {            // q8 = mh*8+i -> m quad
            const uint2 w = lut2[((mh * 8 + i) << 8) + col];
            const __half2 w0 = *(const __half2*)&w.x;
            const __half2 w1 = *(const __half2*)&w.y;
            acc2[2 * i]     = __hadd2(acc2[2 * i],     w0);
            acc2[2 * i + 1] = __hadd2(acc2[2 * i + 1], w1);
        }
    }

    // ---- single-pass output transpose through sBuf (LUT is dead now) ----
    __syncthreads();
    float* sO = (float*)sBuf;            // [128 rows][64 m], 16B-chunk swizzle
    #pragma unroll
    for (int k2 = 0; k2 < 8; ++k2) {
        const int ch = mh * 8 + k2;      // global float4 chunk = m/4
        const float4 v = make_float4(__low2float(acc2[2 * k2]),
                                     __high2float(acc2[2 * k2]),
                                     __low2float(acc2[2 * k2 + 1]),
                                     __high2float(acc2[2 * k2 + 1]));
        *(float4*)&sO[(lr << 6) + ((ch ^ (lr & 15)) << 2)] = v;
    }
    __syncthreads();

    float4* op = (float4*)(out + (size_t)blockIdx.x * (128 * 64));
    #pragma unroll
    for (int j = 0; j < 8; ++j) {        // 2048 float4 = 32 KiB, contiguous
        const int F  = tid + (j << 8);
        const int r2 = F >> 4;
        const int m2 = F & 15;
        op[F] = *(const float4*)&sO[(r2 << 6) + ((m2 ^ (r2 & 15)) << 2)];
    }
}

extern "C" void kernel_launch(void* const* d_in, const int* in_sizes, int n_in,
                              void* d_out, int out_size, void* d_ws, size_t ws_size,
                              hipStream_t stream) {
    const float* I = (const float*)d_in[0];
    const float* A = (const float*)d_in[1];
    const float* T = (const float*)d_in[2];
    const float* L = (const float*)d_in[3];
    float* outp = (float*)d_out;

    const int nblocks = NROWS / 128;   // 1024 blocks x 256 threads, 2 thr/row
    halut_fwd<<<nblocks, 256, 0, stream>>>(I, A, T, L, outp);
}